// Round 1
// 793.775 us; speedup vs baseline: 1.0037x; 1.0037x over previous
//
#include <hip/hip_runtime.h>
#include <hip/hip_bf16.h>

// Potts energy kernel for MI355X.
// B=2, N=4096, K=48, Q=20.
// Outputs (flat concat): U (B,) then U_i (B,N,Q), fp32.
//
// J (629 MB) dominates and every cache line of each 20x20 block is touched by
// the column gather, so the roofline is one coalesced pass over J (~105 us).
// R4: fix the MLP failure. The old loop interleaved each float4 load with a
// divergent LDS-atomic region; exec-mask save/restore between loads kept only
// ~1-2 loads in flight per wave (~1.6 TB/s observed). Now: batch-issue all 15
// coalesced loads into registers first (no exec-mask ops between them), overlap
// the neighbor-state gather under their latency, fence with __syncthreads()
// (drains vmcnt), then run the branchy select/accumulate as a pure VALU/LDS
// phase on register data. 15 KB in flight per wave -> BW-bound.

constexpr int Bc = 2;
constexpr int Nc = 4096;
constexpr int Kc = 48;
constexpr int Qc = 20;
constexpr int NODE_FLOATS = Kc * Qc * Qc;      // 19200
constexpr int NODE_F4     = NODE_FLOATS / 4;   // 4800
constexpr int TPB         = 320;               // 5 waves; 4800 % 320 == 0
constexpr int NITER       = NODE_F4 / TPB;     // 15

__global__ __launch_bounds__(TPB) void potts_node_kernel(
    const int*   __restrict__ S,
    const float* __restrict__ h,
    const float* __restrict__ J,
    const int*   __restrict__ edge_idx,
    float*       __restrict__ U_i_out,   // (B*N*Q)
    float*       __restrict__ node_c)    // (B*N) per-node scalar contribution
{
    const int node = blockIdx.x;          // 0 .. B*N-1
    const int b    = node >> 12;          // node / N (N=4096)
    const int tid  = threadIdx.x;

    __shared__ float Jl[Qc];
    __shared__ int   sj[Kc];
    __shared__ int   s_i_sh;

    // Phase 1: issue ALL 15 coalesced float4 loads back-to-back.
    // No branches / exec-mask ops between them -> 15 loads in flight per wave.
    const float4* Jb = (const float4*)(J + (size_t)node * NODE_FLOATS);
    float4 v[NITER];
    #pragma unroll
    for (int j = 0; j < NITER; ++j) v[j] = Jb[tid + j * TPB];
    // Pin the load cluster: nothing may be scheduled above this point.
    __builtin_amdgcn_sched_barrier(0);

    // Phase 2: prologue gather overlaps the J-load latency.
    if (tid < Qc) Jl[tid] = 0.0f;
    if (tid < Kc) {
        int e = edge_idx[node * Kc + tid];
        sj[tid] = S[b * Nc + e];
    }
    if (tid == 0) s_i_sh = S[node];
    __syncthreads();   // drains vmcnt+lgkmcnt: all v[] and sj[] ready

    // Phase 3: pure VALU/LDS processing on register data.
    #pragma unroll
    for (int j = 0; j < NITER; ++j) {
        const int m = tid + j * TPB;
        // flat float index f = 4*m ; f = k*400 + q*20 + s ; s0 in {0,4,8,12,16}
        int k  = m / 100;              // 100 float4 per k
        int r  = m - k * 100;
        int q  = r / 5;                // 5 float4 per q
        int s0 = (r - q * 5) << 2;
        int d  = sj[k] - s0;
        if ((unsigned)d < 4u) {
            float4 vv = v[j];
            float val = (d == 0) ? vv.x : (d == 1) ? vv.y : (d == 2) ? vv.z : vv.w;
            atomicAdd(&Jl[q], val);
        }
    }
    __syncthreads();

    if (tid < Qc) {
        float ji = Jl[tid];
        float ui = h[node * Qc + tid] + ji;
        U_i_out[node * Qc + tid] = ui;
        if (tid == s_i_sh) {
            // U contribution: (h[s]+J_i[s]) - 0.5*J_i[s] = ui - 0.5*ji
            node_c[node] = ui - 0.5f * ji;
        }
    }
}

__global__ __launch_bounds__(256) void potts_reduce_kernel(
    const float* __restrict__ node_c, float* __restrict__ U)
{
    const int b   = blockIdx.x;
    const int tid = threadIdx.x;
    float s = 0.0f;
    for (int i = tid; i < Nc; i += 256) s += node_c[b * Nc + i];
    #pragma unroll
    for (int off = 32; off > 0; off >>= 1) s += __shfl_down(s, off, 64);
    __shared__ float ws[4];
    if ((tid & 63) == 0) ws[tid >> 6] = s;
    __syncthreads();
    if (tid == 0) U[b] = ws[0] + ws[1] + ws[2] + ws[3];
}

extern "C" void kernel_launch(void* const* d_in, const int* in_sizes, int n_in,
                              void* d_out, int out_size, void* d_ws, size_t ws_size,
                              hipStream_t stream) {
    const int*   S        = (const int*)  d_in[0];
    const float* h        = (const float*)d_in[1];
    const float* J        = (const float*)d_in[2];
    const int*   edge_idx = (const int*)  d_in[3];

    float* out    = (float*)d_out;
    float* U      = out;        // 2 floats
    float* U_i    = out + Bc;   // B*N*Q floats
    float* node_c = (float*)d_ws;

    potts_node_kernel<<<Bc * Nc, TPB, 0, stream>>>(S, h, J, edge_idx, U_i, node_c);
    potts_reduce_kernel<<<Bc, 256, 0, stream>>>(node_c, U);
}